// Round 4
// baseline (852.812 us; speedup 1.0000x reference)
//
#include <hip/hip_runtime.h>
#include <math.h>

// SAE hierarchical fused kernel, fp32-exact.
// R4: (1) W loads forced onto the VECTOR memory path (laundered-zero VGPR in
// the address) -- R1-R3 scalar-loaded W into 64 SGPRs (SGPR_Count=112) with
// full lgkmcnt drains per feature; (2) x row loaded+pinned INSIDE the attempt
// loop so its live range crosses no barriers (R1-R3 spilled it, VGPR=52);
// (3) decode loops fully unrolled so Wd row loads pipeline.

#define D64   64
#define HID1  4096
#define HID2  2048
#define K1    32
#define K2    16
#define ROWS  64
#define NWAVE 16
#define CAP   176

#define FOR16(M) M(0) M(1) M(2) M(3) M(4) M(5) M(6) M(7) \
                 M(8) M(9) M(10) M(11) M(12) M(13) M(14) M(15)
#define FORA(M) M(0) M(1) M(2) M(3) M(4) M(5) M(6) M(7)
#define FORB(M) M(8) M(9) M(10) M(11) M(12) M(13) M(14) M(15)

#define KEEP4(v) asm volatile("" : "+v"(v.x), "+v"(v.y), "+v"(v.z), "+v"(v.w))

__device__ __forceinline__ unsigned long long wave_max_u64(unsigned long long m) {
#pragma unroll
    for (int off = 32; off > 0; off >>= 1) {
        unsigned lo = (unsigned)m, hi = (unsigned)(m >> 32);
        unsigned olo = __shfl_xor(lo, off, 64);
        unsigned ohi = __shfl_xor(hi, off, 64);
        unsigned long long o = ((unsigned long long)ohi << 32) | (unsigned long long)olo;
        if (o > m) m = o;
    }
    return m;
}

__device__ __forceinline__ float wave_sum_f32(float v) {
#pragma unroll
    for (int off = 32; off > 0; off >>= 1) v += __shfl_xor(v, off, 64);
    return v;
}

__global__ __launch_bounds__(1024) void sae_hier_fused(
    const float* __restrict__ x,
    const float* __restrict__ W1,  const float* __restrict__ b1,
    const float* __restrict__ Wd1, const float* __restrict__ bd1,
    const float* __restrict__ W2,  const float* __restrict__ b2,
    const float* __restrict__ Wd2, const float* __restrict__ bd2,
    float* __restrict__ out)
{
    __shared__ uint2 s_buf[ROWS * CAP];
    __shared__ float s_recon[ROWS * 68];
    __shared__ float s_t2[ROWS];
    __shared__ float s_scale[ROWS];
    __shared__ int   s_cnt[ROWS];
    __shared__ int   s_act[ROWS];
    __shared__ int   s_anybad;

    const int tid  = threadIdx.x;
    const int lane = tid & 63;
    const int w    = tid >> 6;
    const int wu   = __builtin_amdgcn_readfirstlane(w);
    const int rowbase = blockIdx.x * ROWS;

    // Opaque zero in a VGPR: forces any address that includes it onto the
    // per-lane (vector) memory path; identical lane addresses broadcast.
    int vzero;
    asm volatile("v_mov_b32 %0, 0" : "=v"(vzero));

    if (tid < ROWS) { s_cnt[tid] = 0; s_scale[tid] = 1.0f; s_act[tid] = 1; }
    __syncthreads();

    // ================= level 0: threshold push (with retry) =================
    for (int attempt = 0; attempt < 8; ++attempt) {
        // ---- x row (lane = local row) minus b_dec, pinned; live range local ----
#define DECLX(kk) float4 x##kk;
        FOR16(DECLX)
#undef DECLX
        {
            const float4* xp = reinterpret_cast<const float4*>(x) + (size_t)(rowbase + lane) * 16;
            const float4* bp = reinterpret_cast<const float4*>(bd1);
#define LOADX(kk) { float4 a = xp[kk]; float4 b = bp[kk]; \
                    x##kk = make_float4(a.x-b.x, a.y-b.y, a.z-b.z, a.w-b.w); \
                    KEEP4(x##kk); }
            FOR16(LOADX)
#undef LOADX
        }
        float tb1;
        {
            float a0 = 0.f, a1 = 0.f, a2 = 0.f, a3 = 0.f;
#define SSX(kk) { a0 = fmaf(x##kk.x, x##kk.x, a0); a1 = fmaf(x##kk.y, x##kk.y, a1); \
                  a2 = fmaf(x##kk.z, x##kk.z, a2); a3 = fmaf(x##kk.w, x##kk.w, a3); }
            FOR16(SSX)
#undef SSX
            tb1 = 0.25f * sqrtf((a0 + a2) + (a1 + a3));   // 2*sigma
        }

        const bool  act = (s_act[lane] != 0);
        const float thr = tb1 * s_scale[lane];
        const int jbase = wu * (HID1 / NWAVE);
#pragma unroll 1
        for (int jj = 0; jj < HID1 / NWAVE; ++jj) {
            const int j = jbase + jj;
            // vzero makes the index formally per-lane -> vector loads.
            const float4* Wp = reinterpret_cast<const float4*>(W1) + ((size_t)j * 16 + vzero);
            float a0 = 0.f, a1 = 0.f, a2 = 0.f, a3 = 0.f;
            {
#define LW(kk) float4 wv##kk = Wp[kk];
#define FM(kk) { a0 = fmaf(wv##kk.x, x##kk.x, a0); a1 = fmaf(wv##kk.y, x##kk.y, a1); \
                 a2 = fmaf(wv##kk.z, x##kk.z, a2); a3 = fmaf(wv##kk.w, x##kk.w, a3); }
                FORA(LW)
                FORA(FM)
                FORB(LW)
                FORB(FM)
#undef LW
#undef FM
            }
            float v = ((a0 + a2) + (a1 + a3)) + b1[j];
            v = fmaxf(v, 0.0f);
            if (act && v > thr) {
                int slot = atomicAdd(&s_cnt[lane], 1);
                if (slot < CAP) s_buf[lane * CAP + slot] = make_uint2(__float_as_uint(v), (unsigned)j);
            }
        }
        __syncthreads();
        if (tid == 0) s_anybad = 0;
        __syncthreads();
        if (tid < ROWS) {
            int c = s_cnt[tid];
            bool lo = (c < K1), hi = (c > CAP);
            bool bad = (lo || hi) && (attempt < 7);
            s_act[tid] = bad ? 1 : 0;
            if (bad) { s_scale[tid] *= (lo ? 0.6f : 1.4f); s_cnt[tid] = 0; atomicAdd(&s_anybad, 1); }
        }
        __syncthreads();
        if (s_anybad == 0) break;
    }

    // ================= level 0: exact select + fused decode =================
#pragma unroll 1
    for (int q = 0; q < ROWS / NWAVE; ++q) {
        const int r = wu * (ROWS / NWAVE) + q;
        int n = s_cnt[r]; if (n > CAP) n = CAP;
        unsigned long long k0 = 0ull, k1 = 0ull, k2 = 0ull;
        if (lane < n)       { uint2 p = s_buf[r * CAP + lane];       k0 = ((unsigned long long)p.x << 32) | (unsigned)(~p.y); }
        if (lane + 64 < n)  { uint2 p = s_buf[r * CAP + lane + 64];  k1 = ((unsigned long long)p.x << 32) | (unsigned)(~p.y); }
        if (lane + 128 < n) { uint2 p = s_buf[r * CAP + lane + 128]; k2 = ((unsigned long long)p.x << 32) | (unsigned)(~p.y); }
        if (k1 > k0) { unsigned long long t = k0; k0 = k1; k1 = t; }
        if (k2 > k1) { unsigned long long t = k1; k1 = k2; k2 = t; }
        if (k1 > k0) { unsigned long long t = k0; k0 = k1; k1 = t; }
        unsigned savhi = 0u, savlo = 0u;
#pragma unroll 1
        for (int t = 0; t < K1; ++t) {
            unsigned long long m = wave_max_u64(k0);
            if (m == 0ull) break;
            if (lane == t) { savhi = (unsigned)(m >> 32); savlo = (unsigned)m; }
            if (k0 == m) { k0 = k1; k1 = k2; k2 = 0ull; }
        }
        float rec = bd1[lane];
#pragma unroll
        for (int t = 0; t < K1; ++t) {
            unsigned mhi = __shfl(savhi, t, 64);
            unsigned mlo = __shfl(savlo, t, 64);
            unsigned idx = (mhi != 0u) ? ~mlo : 0u;
            rec = fmaf(__uint_as_float(mhi), Wd1[(size_t)idx * D64 + lane], rec);
        }
        float e = wave_sum_f32(rec * rec);
        if (lane == 0) s_t2[r] = 0.25f * sqrtf(e);
        s_recon[r * 68 + lane] = rec;
    }
    __syncthreads();

    // ================= level 1 =================
    if (tid < ROWS) { s_cnt[tid] = 0; s_scale[tid] = 1.0f; s_act[tid] = 1; }
    __syncthreads();

    for (int attempt = 0; attempt < 8; ++attempt) {
#define DECLY(kk) float4 y##kk;
        FOR16(DECLY)
#undef DECLY
        {
            const float4* rp = reinterpret_cast<const float4*>(&s_recon[lane * 68]);
#define LOADY(kk) { y##kk = rp[kk]; KEEP4(y##kk); }
            FOR16(LOADY)
#undef LOADY
        }
        const float tb2 = s_t2[lane];
        const bool  act = (s_act[lane] != 0);
        const float thr = tb2 * s_scale[lane];
        const int jbase = wu * (HID2 / NWAVE);
#pragma unroll 1
        for (int jj = 0; jj < HID2 / NWAVE; ++jj) {
            const int j = jbase + jj;
            const float4* Wp = reinterpret_cast<const float4*>(W2) + ((size_t)j * 16 + vzero);
            float a0 = 0.f, a1 = 0.f, a2 = 0.f, a3 = 0.f;
            {
#define LW(kk) float4 wv##kk = Wp[kk];
#define FM(kk) { a0 = fmaf(wv##kk.x, y##kk.x, a0); a1 = fmaf(wv##kk.y, y##kk.y, a1); \
                 a2 = fmaf(wv##kk.z, y##kk.z, a2); a3 = fmaf(wv##kk.w, y##kk.w, a3); }
                FORA(LW)
                FORA(FM)
                FORB(LW)
                FORB(FM)
#undef LW
#undef FM
            }
            float v = ((a0 + a2) + (a1 + a3)) + b2[j];
            v = fmaxf(v, 0.0f);
            if (act && v > thr) {
                int slot = atomicAdd(&s_cnt[lane], 1);
                if (slot < CAP) s_buf[lane * CAP + slot] = make_uint2(__float_as_uint(v), (unsigned)j);
            }
        }
        __syncthreads();
        if (tid == 0) s_anybad = 0;
        __syncthreads();
        if (tid < ROWS) {
            int c = s_cnt[tid];
            bool lo = (c < K2), hi = (c > CAP);
            bool bad = (lo || hi) && (attempt < 7);
            s_act[tid] = bad ? 1 : 0;
            if (bad) { s_scale[tid] *= (lo ? 0.6f : 1.4f); s_cnt[tid] = 0; atomicAdd(&s_anybad, 1); }
        }
        __syncthreads();
        if (s_anybad == 0) break;
    }

    // ============ level 1: select + decode, combine, store ============
#pragma unroll 1
    for (int q = 0; q < ROWS / NWAVE; ++q) {
        const int r = wu * (ROWS / NWAVE) + q;
        int n = s_cnt[r]; if (n > CAP) n = CAP;
        unsigned long long k0 = 0ull, k1 = 0ull, k2 = 0ull;
        if (lane < n)       { uint2 p = s_buf[r * CAP + lane];       k0 = ((unsigned long long)p.x << 32) | (unsigned)(~p.y); }
        if (lane + 64 < n)  { uint2 p = s_buf[r * CAP + lane + 64];  k1 = ((unsigned long long)p.x << 32) | (unsigned)(~p.y); }
        if (lane + 128 < n) { uint2 p = s_buf[r * CAP + lane + 128]; k2 = ((unsigned long long)p.x << 32) | (unsigned)(~p.y); }
        if (k1 > k0) { unsigned long long t = k0; k0 = k1; k1 = t; }
        if (k2 > k1) { unsigned long long t = k1; k1 = k2; k2 = t; }
        if (k1 > k0) { unsigned long long t = k0; k0 = k1; k1 = t; }
        unsigned savhi = 0u, savlo = 0u;
#pragma unroll 1
        for (int t = 0; t < K2; ++t) {
            unsigned long long m = wave_max_u64(k0);
            if (m == 0ull) break;
            if (lane == t) { savhi = (unsigned)(m >> 32); savlo = (unsigned)m; }
            if (k0 == m) { k0 = k1; k1 = k2; k2 = 0ull; }
        }
        float rec1 = bd2[lane];
#pragma unroll
        for (int t = 0; t < K2; ++t) {
            unsigned mhi = __shfl(savhi, t, 64);
            unsigned mlo = __shfl(savlo, t, 64);
            unsigned idx = (mhi != 0u) ? ~mlo : 0u;
            rec1 = fmaf(__uint_as_float(mhi), Wd2[(size_t)idx * D64 + lane], rec1);
        }
        float rec0 = s_recon[r * 68 + lane];
        out[(size_t)(rowbase + r) * D64 + lane] = (1.0f / 1.5f) * rec0 + (0.5f / 1.5f) * rec1;
    }
}

extern "C" void kernel_launch(void* const* d_in, const int* in_sizes, int n_in,
                              void* d_out, int out_size, void* d_ws, size_t ws_size,
                              hipStream_t stream) {
    (void)n_in; (void)out_size; (void)d_ws; (void)ws_size;
    const float* x   = (const float*)d_in[0];
    const float* W1  = (const float*)d_in[1];
    const float* b1  = (const float*)d_in[2];
    const float* Wd1 = (const float*)d_in[3];
    const float* bd1 = (const float*)d_in[4];
    const float* W2  = (const float*)d_in[5];
    const float* b2  = (const float*)d_in[6];
    const float* Wd2 = (const float*)d_in[7];
    const float* bd2 = (const float*)d_in[8];

    const int batch = in_sizes[0] / D64;     // 16384
    const int grid  = batch / ROWS;          // 256 blocks

    sae_hier_fused<<<grid, 1024, 0, stream>>>(x, W1, b1, Wd1, bd1, W2, b2, Wd2, bd2,
                                              (float*)d_out);
}

// Round 5
// 848.709 us; speedup vs baseline: 1.0048x; 1.0048x over previous
//
#include <hip/hip_runtime.h>
#include <math.h>

// SAE hierarchical fused kernel, fp32-exact.
// R5 root-cause fix: __launch_bounds__(1024, 4). R1-R4's allocator targeted
// the DEFAULT 8 waves/EU -> 64-VGPR budget -> x row (64 floats) could never
// be register-resident (R1-R3: remat/sink into the loop; R4: scratch spill,
// WRITE_SIZE 4x). With LDS=109KB only 1 block/CU fits anyway (4 waves/EU),
// so min-waves-per-eu=4 legitimately raises the budget to 128 VGPRs.
// Structure: lane = row (x row pinned in 64 VGPRs), wave = feature slice,
// W on the vector path (laundered-zero VGPR address), 8+8 load/FMA batching.
// Top-k: sigma-threshold candidate push into LDS + count-check retry, exact
// u64-key selection (value bits desc, lower index tie-break = jax).

#define D64   64
#define HID1  4096
#define HID2  2048
#define K1    32
#define K2    16
#define ROWS  64
#define NWAVE 16
#define CAP   176

#define FOR16(M) M(0) M(1) M(2) M(3) M(4) M(5) M(6) M(7) \
                 M(8) M(9) M(10) M(11) M(12) M(13) M(14) M(15)
#define FORA(M) M(0) M(1) M(2) M(3) M(4) M(5) M(6) M(7)
#define FORB(M) M(8) M(9) M(10) M(11) M(12) M(13) M(14) M(15)

#define KEEP4(v) asm volatile("" : "+v"(v.x), "+v"(v.y), "+v"(v.z), "+v"(v.w))

__device__ __forceinline__ unsigned long long wave_max_u64(unsigned long long m) {
#pragma unroll
    for (int off = 32; off > 0; off >>= 1) {
        unsigned lo = (unsigned)m, hi = (unsigned)(m >> 32);
        unsigned olo = __shfl_xor(lo, off, 64);
        unsigned ohi = __shfl_xor(hi, off, 64);
        unsigned long long o = ((unsigned long long)ohi << 32) | (unsigned long long)olo;
        if (o > m) m = o;
    }
    return m;
}

__device__ __forceinline__ float wave_sum_f32(float v) {
#pragma unroll
    for (int off = 32; off > 0; off >>= 1) v += __shfl_xor(v, off, 64);
    return v;
}

__global__ __launch_bounds__(1024, 4) void sae_hier_fused(
    const float* __restrict__ x,
    const float* __restrict__ W1,  const float* __restrict__ b1,
    const float* __restrict__ Wd1, const float* __restrict__ bd1,
    const float* __restrict__ W2,  const float* __restrict__ b2,
    const float* __restrict__ Wd2, const float* __restrict__ bd2,
    float* __restrict__ out)
{
    __shared__ uint2 s_buf[ROWS * CAP];
    __shared__ float s_recon[ROWS * 68];
    __shared__ float s_t2[ROWS];
    __shared__ float s_scale[ROWS];
    __shared__ int   s_cnt[ROWS];
    __shared__ int   s_act[ROWS];
    __shared__ int   s_anybad;

    const int tid  = threadIdx.x;
    const int lane = tid & 63;
    const int w    = tid >> 6;
    const int wu   = __builtin_amdgcn_readfirstlane(w);
    const int rowbase = blockIdx.x * ROWS;

    // Opaque zero in a VGPR: any address including it goes on the vector
    // memory path (uniform lane addresses coalesce to one broadcast txn).
    int vzero;
    asm volatile("v_mov_b32 %0, 0" : "=v"(vzero));

    if (tid < ROWS) { s_cnt[tid] = 0; s_scale[tid] = 1.0f; s_act[tid] = 1; }
    __syncthreads();

    // ---- x row (lane = local row) minus b_dec, pinned in 64 VGPRs ----
#define DECLX(kk) float4 x##kk;
    FOR16(DECLX)
#undef DECLX
    {
        const float4* xp = reinterpret_cast<const float4*>(x) + (size_t)(rowbase + lane) * 16;
        const float4* bp = reinterpret_cast<const float4*>(bd1);
#define LOADX(kk) { float4 a = xp[kk]; float4 b = bp[kk]; \
                    x##kk = make_float4(a.x-b.x, a.y-b.y, a.z-b.z, a.w-b.w); \
                    KEEP4(x##kk); }
        FOR16(LOADX)
#undef LOADX
    }
    float tb1;
    {
        float a0 = 0.f, a1 = 0.f, a2 = 0.f, a3 = 0.f;
#define SSX(kk) { a0 = fmaf(x##kk.x, x##kk.x, a0); a1 = fmaf(x##kk.y, x##kk.y, a1); \
                  a2 = fmaf(x##kk.z, x##kk.z, a2); a3 = fmaf(x##kk.w, x##kk.w, a3); }
        FOR16(SSX)
#undef SSX
        tb1 = 0.25f * sqrtf((a0 + a2) + (a1 + a3));   // 2*sigma, sigma = ||x-b_dec||/8
    }

    // ================= level 0: threshold push (with retry) =================
    for (int attempt = 0; attempt < 8; ++attempt) {
        const bool  act = (s_act[lane] != 0);
        const float thr = tb1 * s_scale[lane];
        const int jbase = wu * (HID1 / NWAVE);
#pragma unroll 1
        for (int jj = 0; jj < HID1 / NWAVE; ++jj) {
            const int j = jbase + jj;
            const float4* Wp = reinterpret_cast<const float4*>(W1) + ((size_t)j * 16 + vzero);
            float a0 = 0.f, a1 = 0.f, a2 = 0.f, a3 = 0.f;
            {
#define LW(kk) float4 wv##kk = Wp[kk];
#define FM(kk) { a0 = fmaf(wv##kk.x, x##kk.x, a0); a1 = fmaf(wv##kk.y, x##kk.y, a1); \
                 a2 = fmaf(wv##kk.z, x##kk.z, a2); a3 = fmaf(wv##kk.w, x##kk.w, a3); }
                FORA(LW)
                FORA(FM)
                FORB(LW)
                FORB(FM)
#undef LW
#undef FM
            }
            float v = ((a0 + a2) + (a1 + a3)) + b1[j];
            v = fmaxf(v, 0.0f);
            if (act && v > thr) {
                int slot = atomicAdd(&s_cnt[lane], 1);
                if (slot < CAP) s_buf[lane * CAP + slot] = make_uint2(__float_as_uint(v), (unsigned)j);
            }
        }
        __syncthreads();
        if (tid == 0) s_anybad = 0;
        __syncthreads();
        if (tid < ROWS) {
            int c = s_cnt[tid];
            bool lo = (c < K1), hi = (c > CAP);
            bool bad = (lo || hi) && (attempt < 7);
            s_act[tid] = bad ? 1 : 0;
            if (bad) { s_scale[tid] *= (lo ? 0.6f : 1.4f); s_cnt[tid] = 0; atomicAdd(&s_anybad, 1); }
        }
        __syncthreads();
        if (s_anybad == 0) break;
    }

    // ================= level 0: exact select + fused decode =================
#pragma unroll 1
    for (int q = 0; q < ROWS / NWAVE; ++q) {
        const int r = wu * (ROWS / NWAVE) + q;
        int n = s_cnt[r]; if (n > CAP) n = CAP;
        unsigned long long k0 = 0ull, k1 = 0ull, k2 = 0ull;
        if (lane < n)       { uint2 p = s_buf[r * CAP + lane];       k0 = ((unsigned long long)p.x << 32) | (unsigned)(~p.y); }
        if (lane + 64 < n)  { uint2 p = s_buf[r * CAP + lane + 64];  k1 = ((unsigned long long)p.x << 32) | (unsigned)(~p.y); }
        if (lane + 128 < n) { uint2 p = s_buf[r * CAP + lane + 128]; k2 = ((unsigned long long)p.x << 32) | (unsigned)(~p.y); }
        if (k1 > k0) { unsigned long long t = k0; k0 = k1; k1 = t; }
        if (k2 > k1) { unsigned long long t = k1; k1 = k2; k2 = t; }
        if (k1 > k0) { unsigned long long t = k0; k0 = k1; k1 = t; }
        unsigned savhi = 0u, savlo = 0u;
#pragma unroll 1
        for (int t = 0; t < K1; ++t) {
            unsigned long long m = wave_max_u64(k0);
            if (m == 0ull) break;
            if (lane == t) { savhi = (unsigned)(m >> 32); savlo = (unsigned)m; }
            if (k0 == m) { k0 = k1; k1 = k2; k2 = 0ull; }
        }
        float rec = bd1[lane];
#pragma unroll
        for (int t = 0; t < K1; ++t) {
            unsigned mhi = __shfl(savhi, t, 64);
            unsigned mlo = __shfl(savlo, t, 64);
            unsigned idx = (mhi != 0u) ? ~mlo : 0u;
            rec = fmaf(__uint_as_float(mhi), Wd1[(size_t)idx * D64 + lane], rec);
        }
        float e = wave_sum_f32(rec * rec);
        if (lane == 0) s_t2[r] = 0.25f * sqrtf(e);
        s_recon[r * 68 + lane] = rec;
    }
    __syncthreads();

    // ================= level 1 =================
    if (tid < ROWS) { s_cnt[tid] = 0; s_scale[tid] = 1.0f; s_act[tid] = 1; }
    __syncthreads();

#define DECLY(kk) float4 y##kk;
    FOR16(DECLY)
#undef DECLY
    {
        const float4* rp = reinterpret_cast<const float4*>(&s_recon[lane * 68]);
#define LOADY(kk) { y##kk = rp[kk]; KEEP4(y##kk); }
        FOR16(LOADY)
#undef LOADY
    }
    const float tb2 = s_t2[lane];

    for (int attempt = 0; attempt < 8; ++attempt) {
        const bool  act = (s_act[lane] != 0);
        const float thr = tb2 * s_scale[lane];
        const int jbase = wu * (HID2 / NWAVE);
#pragma unroll 1
        for (int jj = 0; jj < HID2 / NWAVE; ++jj) {
            const int j = jbase + jj;
            const float4* Wp = reinterpret_cast<const float4*>(W2) + ((size_t)j * 16 + vzero);
            float a0 = 0.f, a1 = 0.f, a2 = 0.f, a3 = 0.f;
            {
#define LW(kk) float4 wv##kk = Wp[kk];
#define FM(kk) { a0 = fmaf(wv##kk.x, y##kk.x, a0); a1 = fmaf(wv##kk.y, y##kk.y, a1); \
                 a2 = fmaf(wv##kk.z, y##kk.z, a2); a3 = fmaf(wv##kk.w, y##kk.w, a3); }
                FORA(LW)
                FORA(FM)
                FORB(LW)
                FORB(FM)
#undef LW
#undef FM
            }
            float v = ((a0 + a2) + (a1 + a3)) + b2[j];
            v = fmaxf(v, 0.0f);
            if (act && v > thr) {
                int slot = atomicAdd(&s_cnt[lane], 1);
                if (slot < CAP) s_buf[lane * CAP + slot] = make_uint2(__float_as_uint(v), (unsigned)j);
            }
        }
        __syncthreads();
        if (tid == 0) s_anybad = 0;
        __syncthreads();
        if (tid < ROWS) {
            int c = s_cnt[tid];
            bool lo = (c < K2), hi = (c > CAP);
            bool bad = (lo || hi) && (attempt < 7);
            s_act[tid] = bad ? 1 : 0;
            if (bad) { s_scale[tid] *= (lo ? 0.6f : 1.4f); s_cnt[tid] = 0; atomicAdd(&s_anybad, 1); }
        }
        __syncthreads();
        if (s_anybad == 0) break;
    }

    // ============ level 1: select + decode, combine, store ============
#pragma unroll 1
    for (int q = 0; q < ROWS / NWAVE; ++q) {
        const int r = wu * (ROWS / NWAVE) + q;
        int n = s_cnt[r]; if (n > CAP) n = CAP;
        unsigned long long k0 = 0ull, k1 = 0ull, k2 = 0ull;
        if (lane < n)       { uint2 p = s_buf[r * CAP + lane];       k0 = ((unsigned long long)p.x << 32) | (unsigned)(~p.y); }
        if (lane + 64 < n)  { uint2 p = s_buf[r * CAP + lane + 64];  k1 = ((unsigned long long)p.x << 32) | (unsigned)(~p.y); }
        if (lane + 128 < n) { uint2 p = s_buf[r * CAP + lane + 128]; k2 = ((unsigned long long)p.x << 32) | (unsigned)(~p.y); }
        if (k1 > k0) { unsigned long long t = k0; k0 = k1; k1 = t; }
        if (k2 > k1) { unsigned long long t = k1; k1 = k2; k2 = t; }
        if (k1 > k0) { unsigned long long t = k0; k0 = k1; k1 = t; }
        unsigned savhi = 0u, savlo = 0u;
#pragma unroll 1
        for (int t = 0; t < K2; ++t) {
            unsigned long long m = wave_max_u64(k0);
            if (m == 0ull) break;
            if (lane == t) { savhi = (unsigned)(m >> 32); savlo = (unsigned)m; }
            if (k0 == m) { k0 = k1; k1 = k2; k2 = 0ull; }
        }
        float rec1 = bd2[lane];
#pragma unroll
        for (int t = 0; t < K2; ++t) {
            unsigned mhi = __shfl(savhi, t, 64);
            unsigned mlo = __shfl(savlo, t, 64);
            unsigned idx = (mhi != 0u) ? ~mlo : 0u;
            rec1 = fmaf(__uint_as_float(mhi), Wd2[(size_t)idx * D64 + lane], rec1);
        }
        float rec0 = s_recon[r * 68 + lane];
        out[(size_t)(rowbase + r) * D64 + lane] = (1.0f / 1.5f) * rec0 + (0.5f / 1.5f) * rec1;
    }
}

extern "C" void kernel_launch(void* const* d_in, const int* in_sizes, int n_in,
                              void* d_out, int out_size, void* d_ws, size_t ws_size,
                              hipStream_t stream) {
    (void)n_in; (void)out_size; (void)d_ws; (void)ws_size;
    const float* x   = (const float*)d_in[0];
    const float* W1  = (const float*)d_in[1];
    const float* b1  = (const float*)d_in[2];
    const float* Wd1 = (const float*)d_in[3];
    const float* bd1 = (const float*)d_in[4];
    const float* W2  = (const float*)d_in[5];
    const float* b2  = (const float*)d_in[6];
    const float* Wd2 = (const float*)d_in[7];
    const float* bd2 = (const float*)d_in[8];

    const int batch = in_sizes[0] / D64;     // 16384
    const int grid  = batch / ROWS;          // 256 blocks, 1 per CU

    sae_hier_fused<<<grid, 1024, 0, stream>>>(x, W1, b1, Wd1, bd1, W2, b2, Wd2, bd2,
                                              (float*)d_out);
}

// Round 6
// 828.956 us; speedup vs baseline: 1.0288x; 1.0238x over previous
//
#include <hip/hip_runtime.h>
#include <math.h>

// SAE hierarchical fused kernel, fp32-exact.
// R6 restructure: stop fighting the register allocator (R1-R5: it caps at
// 64 VGPR for 1024-thread blocks and spills/remats any 64-float row).
// x lives in LDS in an XOR-swizzled layout (chunk q of row r at float4 slot
// q^(r&7)) -> lane=row ds_read_b128 is bank-conflict-free. Inner loop does
// 8 features per x-read pass: 1 ds_read_b128 + 8 uniform-address W loads
// (laundered-VGPR base + imm offsets -> vector path broadcast) + 32 FMA.
// Per-thread state ~55 VGPR: fits the 64-reg budget, no spill.
// recon0 is written back into the same swizzled buffer for level 1.
// Top-k: sigma-threshold push + count-check retry, exact u64-key selection.

#define D64   64
#define HID1  4096
#define HID2  2048
#define K1    32
#define K2    16
#define ROWS  64
#define NWAVE 16
#define CAP   176
#define GF    8

#define FORA(M) M(0) M(1) M(2) M(3) M(4) M(5) M(6) M(7)

__device__ __forceinline__ unsigned long long wave_max_u64(unsigned long long m) {
#pragma unroll
    for (int off = 32; off > 0; off >>= 1) {
        unsigned lo = (unsigned)m, hi = (unsigned)(m >> 32);
        unsigned olo = __shfl_xor(lo, off, 64);
        unsigned ohi = __shfl_xor(hi, off, 64);
        unsigned long long o = ((unsigned long long)ohi << 32) | (unsigned long long)olo;
        if (o > m) m = o;
    }
    return m;
}

__device__ __forceinline__ float wave_sum_f32(float v) {
#pragma unroll
    for (int off = 32; off > 0; off >>= 1) v += __shfl_xor(v, off, 64);
    return v;
}

__global__ __launch_bounds__(1024)
__attribute__((amdgpu_waves_per_eu(4, 4)))
void sae_hier_fused(
    const float* __restrict__ x,
    const float* __restrict__ W1,  const float* __restrict__ b1,
    const float* __restrict__ Wd1, const float* __restrict__ bd1,
    const float* __restrict__ W2,  const float* __restrict__ b2,
    const float* __restrict__ Wd2, const float* __restrict__ bd2,
    float* __restrict__ out)
{
    __shared__ uint2 s_buf[ROWS * CAP];            // (valbits, j) candidates per row
    __shared__ __align__(16) float s_x[ROWS * D64];// x-b_dec, then recon0 (swizzled)
    __shared__ float s_t2[ROWS];
    __shared__ float s_scale[ROWS];
    __shared__ int   s_cnt[ROWS];
    __shared__ int   s_act[ROWS];
    __shared__ int   s_anybad;

    const int tid  = threadIdx.x;
    const int lane = tid & 63;
    const int w    = tid >> 6;
    const int wu   = __builtin_amdgcn_readfirstlane(w);
    const int rowbase = blockIdx.x * ROWS;

    // Opaque zero VGPR: any address including it stays on the vector memory
    // path (uniform lane addresses coalesce to a broadcast transaction).
    int vzero;
    asm volatile("v_mov_b32 %0, 0" : "=v"(vzero));

    if (tid < ROWS) { s_cnt[tid] = 0; s_scale[tid] = 1.0f; s_act[tid] = 1; }

    // ---- stage (x - b_dec) into swizzled LDS; fully coalesced global read ----
    {
        const int r = tid >> 4;          // local row 0..63
        const int q = tid & 15;          // float4 chunk 0..15
        float4 a = reinterpret_cast<const float4*>(x)[(size_t)(rowbase + r) * 16 + q];
        float4 b = reinterpret_cast<const float4*>(bd1)[q];
        float4 v = make_float4(a.x - b.x, a.y - b.y, a.z - b.z, a.w - b.w);
        *reinterpret_cast<float4*>(&s_x[r * D64 + 4 * (q ^ (r & 7))]) = v;
    }
    __syncthreads();

    // ---- per-lane (row) threshold base: 2*sigma = ||x - b_dec|| / 4 ----
    float tb1;
    {
        float ss = 0.f;
#pragma unroll 4
        for (int kk = 0; kk < 16; ++kk) {
            float4 c = *reinterpret_cast<const float4*>(&s_x[lane * D64 + 4 * (kk ^ (lane & 7))]);
            ss = fmaf(c.x, c.x, ss); ss = fmaf(c.y, c.y, ss);
            ss = fmaf(c.z, c.z, ss); ss = fmaf(c.w, c.w, ss);
        }
        tb1 = 0.25f * sqrtf(ss);
    }

#define PUSH1(aF, bF, jF, KCAP) { float v = fmaxf((aF) + (bF), 0.0f); \
    if (act && v > thr) { int slot = atomicAdd(&s_cnt[lane], 1); \
        if (slot < CAP) s_buf[lane * CAP + slot] = make_uint2(__float_as_uint(v), (unsigned)(jF)); } }

    // ================= level 0: threshold push (with retry) =================
    for (int attempt = 0; attempt < 8; ++attempt) {
        const bool  act = (s_act[lane] != 0);
        const float thr = tb1 * s_scale[lane];
        const int jbase = wu * (HID1 / NWAVE);
#pragma unroll 1
        for (int g = 0; g < (HID1 / NWAVE) / GF; ++g) {
            const int j0 = jbase + g * GF;
            const float* Wb = W1 + (size_t)j0 * D64 + vzero;   // vector path
#define DECLA(f) float a##f = 0.f;
            FORA(DECLA)
#undef DECLA
#pragma unroll 1
            for (int kk = 0; kk < 16; ++kk) {
                const float4 xv = *reinterpret_cast<const float4*>(
                    &s_x[lane * D64 + 4 * (kk ^ (lane & 7))]);
                const float4* wp = reinterpret_cast<const float4*>(Wb) + kk;
#define FMA8(f) { float4 wv = wp[(f) * 16]; \
                  a##f = fmaf(wv.x, xv.x, a##f); a##f = fmaf(wv.y, xv.y, a##f); \
                  a##f = fmaf(wv.z, xv.z, a##f); a##f = fmaf(wv.w, xv.w, a##f); }
                FORA(FMA8)
#undef FMA8
            }
            const float4 bA = *reinterpret_cast<const float4*>(b1 + j0 + vzero);
            const float4 bB = *reinterpret_cast<const float4*>(b1 + j0 + 4 + vzero);
            PUSH1(a0, bA.x, j0 + 0, K1) PUSH1(a1, bA.y, j0 + 1, K1)
            PUSH1(a2, bA.z, j0 + 2, K1) PUSH1(a3, bA.w, j0 + 3, K1)
            PUSH1(a4, bB.x, j0 + 4, K1) PUSH1(a5, bB.y, j0 + 5, K1)
            PUSH1(a6, bB.z, j0 + 6, K1) PUSH1(a7, bB.w, j0 + 7, K1)
        }
        __syncthreads();
        if (tid == 0) s_anybad = 0;
        __syncthreads();
        if (tid < ROWS) {
            int c = s_cnt[tid];
            bool lo = (c < K1), hi = (c > CAP);
            bool bad = (lo || hi) && (attempt < 7);
            s_act[tid] = bad ? 1 : 0;
            if (bad) { s_scale[tid] *= (lo ? 0.6f : 1.4f); s_cnt[tid] = 0; atomicAdd(&s_anybad, 1); }
        }
        __syncthreads();
        if (s_anybad == 0) break;
    }

    // ===== level 0: exact select + fused decode; recon0 -> swizzled s_x =====
#pragma unroll 1
    for (int q = 0; q < ROWS / NWAVE; ++q) {
        const int r = wu * (ROWS / NWAVE) + q;
        int n = s_cnt[r]; if (n > CAP) n = CAP;
        unsigned long long k0 = 0ull, k1 = 0ull, k2 = 0ull;
        if (lane < n)       { uint2 p = s_buf[r * CAP + lane];       k0 = ((unsigned long long)p.x << 32) | (unsigned)(~p.y); }
        if (lane + 64 < n)  { uint2 p = s_buf[r * CAP + lane + 64];  k1 = ((unsigned long long)p.x << 32) | (unsigned)(~p.y); }
        if (lane + 128 < n) { uint2 p = s_buf[r * CAP + lane + 128]; k2 = ((unsigned long long)p.x << 32) | (unsigned)(~p.y); }
        if (k1 > k0) { unsigned long long t = k0; k0 = k1; k1 = t; }
        if (k2 > k1) { unsigned long long t = k1; k1 = k2; k2 = t; }
        if (k1 > k0) { unsigned long long t = k0; k0 = k1; k1 = t; }
        unsigned savhi = 0u, savlo = 0u;
#pragma unroll 1
        for (int t = 0; t < K1; ++t) {
            unsigned long long m = wave_max_u64(k0);
            if (m == 0ull) break;
            if (lane == t) { savhi = (unsigned)(m >> 32); savlo = (unsigned)m; }
            if (k0 == m) { k0 = k1; k1 = k2; k2 = 0ull; }
        }
        float rec = bd1[lane];
#pragma unroll
        for (int t = 0; t < K1; ++t) {
            unsigned mhi = __shfl(savhi, t, 64);
            unsigned mlo = __shfl(savlo, t, 64);
            unsigned idx = (mhi != 0u) ? ~mlo : 0u;
            rec = fmaf(__uint_as_float(mhi), Wd1[(size_t)idx * D64 + lane], rec);
        }
        float e = wave_sum_f32(rec * rec);
        if (lane == 0) s_t2[r] = 0.25f * sqrtf(e);
        // write recon0[r][lane] into swizzled slot (chunk lane>>2, pos lane&3)
        s_x[r * D64 + 4 * ((lane >> 2) ^ (r & 7)) + (lane & 3)] = rec;
    }
    __syncthreads();

    // ================= level 1 =================
    if (tid < ROWS) { s_cnt[tid] = 0; s_scale[tid] = 1.0f; s_act[tid] = 1; }
    __syncthreads();

    const float tb2 = s_t2[lane];

    for (int attempt = 0; attempt < 8; ++attempt) {
        const bool  act = (s_act[lane] != 0);
        const float thr = tb2 * s_scale[lane];
        const int jbase = wu * (HID2 / NWAVE);
#pragma unroll 1
        for (int g = 0; g < (HID2 / NWAVE) / GF; ++g) {
            const int j0 = jbase + g * GF;
            const float* Wb = W2 + (size_t)j0 * D64 + vzero;
#define DECLA(f) float a##f = 0.f;
            FORA(DECLA)
#undef DECLA
#pragma unroll 1
            for (int kk = 0; kk < 16; ++kk) {
                const float4 xv = *reinterpret_cast<const float4*>(
                    &s_x[lane * D64 + 4 * (kk ^ (lane & 7))]);
                const float4* wp = reinterpret_cast<const float4*>(Wb) + kk;
#define FMA8(f) { float4 wv = wp[(f) * 16]; \
                  a##f = fmaf(wv.x, xv.x, a##f); a##f = fmaf(wv.y, xv.y, a##f); \
                  a##f = fmaf(wv.z, xv.z, a##f); a##f = fmaf(wv.w, xv.w, a##f); }
                FORA(FMA8)
#undef FMA8
            }
            const float4 bA = *reinterpret_cast<const float4*>(b2 + j0 + vzero);
            const float4 bB = *reinterpret_cast<const float4*>(b2 + j0 + 4 + vzero);
            PUSH1(a0, bA.x, j0 + 0, K2) PUSH1(a1, bA.y, j0 + 1, K2)
            PUSH1(a2, bA.z, j0 + 2, K2) PUSH1(a3, bA.w, j0 + 3, K2)
            PUSH1(a4, bB.x, j0 + 4, K2) PUSH1(a5, bB.y, j0 + 5, K2)
            PUSH1(a6, bB.z, j0 + 6, K2) PUSH1(a7, bB.w, j0 + 7, K2)
        }
        __syncthreads();
        if (tid == 0) s_anybad = 0;
        __syncthreads();
        if (tid < ROWS) {
            int c = s_cnt[tid];
            bool lo = (c < K2), hi = (c > CAP);
            bool bad = (lo || hi) && (attempt < 7);
            s_act[tid] = bad ? 1 : 0;
            if (bad) { s_scale[tid] *= (lo ? 0.6f : 1.4f); s_cnt[tid] = 0; atomicAdd(&s_anybad, 1); }
        }
        __syncthreads();
        if (s_anybad == 0) break;
    }

    // ============ level 1: select + decode, combine, store ============
#pragma unroll 1
    for (int q = 0; q < ROWS / NWAVE; ++q) {
        const int r = wu * (ROWS / NWAVE) + q;
        int n = s_cnt[r]; if (n > CAP) n = CAP;
        unsigned long long k0 = 0ull, k1 = 0ull, k2 = 0ull;
        if (lane < n)       { uint2 p = s_buf[r * CAP + lane];       k0 = ((unsigned long long)p.x << 32) | (unsigned)(~p.y); }
        if (lane + 64 < n)  { uint2 p = s_buf[r * CAP + lane + 64];  k1 = ((unsigned long long)p.x << 32) | (unsigned)(~p.y); }
        if (lane + 128 < n) { uint2 p = s_buf[r * CAP + lane + 128]; k2 = ((unsigned long long)p.x << 32) | (unsigned)(~p.y); }
        if (k1 > k0) { unsigned long long t = k0; k0 = k1; k1 = t; }
        if (k2 > k1) { unsigned long long t = k1; k1 = k2; k2 = t; }
        if (k1 > k0) { unsigned long long t = k0; k0 = k1; k1 = t; }
        unsigned savhi = 0u, savlo = 0u;
#pragma unroll 1
        for (int t = 0; t < K2; ++t) {
            unsigned long long m = wave_max_u64(k0);
            if (m == 0ull) break;
            if (lane == t) { savhi = (unsigned)(m >> 32); savlo = (unsigned)m; }
            if (k0 == m) { k0 = k1; k1 = k2; k2 = 0ull; }
        }
        float rec1 = bd2[lane];
#pragma unroll
        for (int t = 0; t < K2; ++t) {
            unsigned mhi = __shfl(savhi, t, 64);
            unsigned mlo = __shfl(savlo, t, 64);
            unsigned idx = (mhi != 0u) ? ~mlo : 0u;
            rec1 = fmaf(__uint_as_float(mhi), Wd2[(size_t)idx * D64 + lane], rec1);
        }
        float rec0 = s_x[r * D64 + 4 * ((lane >> 2) ^ (r & 7)) + (lane & 3)];
        out[(size_t)(rowbase + r) * D64 + lane] = (1.0f / 1.5f) * rec0 + (0.5f / 1.5f) * rec1;
    }
}

extern "C" void kernel_launch(void* const* d_in, const int* in_sizes, int n_in,
                              void* d_out, int out_size, void* d_ws, size_t ws_size,
                              hipStream_t stream) {
    (void)n_in; (void)out_size; (void)d_ws; (void)ws_size;
    const float* x   = (const float*)d_in[0];
    const float* W1  = (const float*)d_in[1];
    const float* b1  = (const float*)d_in[2];
    const float* Wd1 = (const float*)d_in[3];
    const float* bd1 = (const float*)d_in[4];
    const float* W2  = (const float*)d_in[5];
    const float* b2  = (const float*)d_in[6];
    const float* Wd2 = (const float*)d_in[7];
    const float* bd2 = (const float*)d_in[8];

    const int batch = in_sizes[0] / D64;     // 16384
    const int grid  = batch / ROWS;          // 256 blocks, 1 per CU

    sae_hier_fused<<<grid, 1024, 0, stream>>>(x, W1, b1, Wd1, bd1, W2, b2, Wd2, bd2,
                                              (float*)d_out);
}

// Round 7
// 259.667 us; speedup vs baseline: 3.2843x; 3.1924x over previous
//
#include <hip/hip_runtime.h>
#include <math.h>

// SAE hierarchical, R7: MFMA bf16-hi approx GEMM + exact fp32 rescue.
// R1-R6 lesson: allocator pins 1024-thread blocks at ~52-64 VGPR; any design
// needing a register-resident 64-float row spills/remats. So: matrix cores.
//  1) approx pre-acts via mfma_f32_16x16x32_bf16 on bf16-RTNE(x), bf16-RTNE(W)
//     (error <= ~0.03 deterministic; push-threshold margin ~0.4 -> candidate
//     set provably contains true top-k)
//  2) push candidates (approx > 2sigma) into LDS, count-check retry
//  3) exact fp32 recompute of every candidate (4/wave parallel, butterfly)
//  4) exact u64-key top-k (value desc, lower index tie-break) + decode
// LDS swizzle: 16B k-blocks XORed with (row&7) -> ~2-way residual conflicts.

#define D64   64
#define ROWS  64
#define CAP   160
#define FTILE 256
#define HID1  4096
#define HID2  2048
#define K1    32
#define K2    16

typedef __attribute__((ext_vector_type(8))) short bf16x8;
typedef __attribute__((ext_vector_type(4))) float f32x4;

__device__ __forceinline__ unsigned short f2bf(float f) {
    unsigned u = __float_as_uint(f);
    return (unsigned short)((u + 0x7FFFu + ((u >> 16) & 1u)) >> 16);
}

__device__ __forceinline__ unsigned long long wave_max_u64(unsigned long long m) {
#pragma unroll
    for (int off = 32; off > 0; off >>= 1) {
        unsigned lo = (unsigned)m, hi = (unsigned)(m >> 32);
        unsigned olo = __shfl_xor(lo, off, 64);
        unsigned ohi = __shfl_xor(hi, off, 64);
        unsigned long long o = ((unsigned long long)ohi << 32) | (unsigned long long)olo;
        if (o > m) m = o;
    }
    return m;
}

__device__ __forceinline__ float wave_sum_f32(float v) {
#pragma unroll
    for (int off = 32; off > 0; off >>= 1) v += __shfl_xor(v, off, 64);
    return v;
}

__global__ __launch_bounds__(1024) void sae_hier_mfma(
    const float* __restrict__ x,
    const float* __restrict__ W1,  const float* __restrict__ b1,
    const float* __restrict__ Wd1, const float* __restrict__ bd1,
    const float* __restrict__ W2,  const float* __restrict__ b2,
    const float* __restrict__ Wd2, const float* __restrict__ bd2,
    float* __restrict__ out)
{
    __shared__ uint2 s_buf[ROWS * CAP];                       // 80 KB candidates
    __shared__ __align__(16) float s_xf32[ROWS * D64];        // 16 KB exact input
    __shared__ __align__(16) unsigned short s_ah[ROWS * D64]; // 8 KB bf16-hi A
    __shared__ __align__(16) unsigned short s_b[FTILE * D64]; // 32 KB bf16-hi B
    __shared__ float s_sig[ROWS];
    __shared__ float s_thr[ROWS];
    __shared__ float s_scale[ROWS];
    __shared__ int   s_cnt[ROWS];
    __shared__ int   s_act[ROWS];
    __shared__ int   s_anybad;

    const int tid  = threadIdx.x;
    const int lane = tid & 63;
    const int wu   = __builtin_amdgcn_readfirstlane(tid >> 6);
    const int rowbase = blockIdx.x * ROWS;

    // ---- stage (x - b_dec): fp32 (exact) + bf16-hi (swizzled) + sigma ----
    {
        const int r = tid >> 4, q = tid & 15;
        float4 a = ((const float4*)x)[(size_t)(rowbase + r) * 16 + q];
        float4 b = ((const float4*)bd1)[q];
        float4 v = make_float4(a.x - b.x, a.y - b.y, a.z - b.z, a.w - b.w);
        ((float4*)s_xf32)[r * 16 + q] = v;
        unsigned long long pk =  (unsigned long long)f2bf(v.x)
                              | ((unsigned long long)f2bf(v.y) << 16)
                              | ((unsigned long long)f2bf(v.z) << 32)
                              | ((unsigned long long)f2bf(v.w) << 48);
        *(unsigned long long*)&s_ah[r * D64 + 8 * ((q >> 1) ^ (r & 7)) + (q & 1) * 4] = pk;
        float ss = fmaf(v.x, v.x, fmaf(v.y, v.y, fmaf(v.z, v.z, v.w * v.w)));
        ss += __shfl_xor(ss, 1, 64); ss += __shfl_xor(ss, 2, 64);
        ss += __shfl_xor(ss, 4, 64); ss += __shfl_xor(ss, 8, 64);
        if (q == 0) s_sig[r] = 0.25f * sqrtf(ss);     // 2*sigma = ||.||/4
    }

    const int wr = wu & 3, wc = wu >> 2;     // wave -> 16-row group, 64-col group
    const int g  = lane >> 4;
    const int arow = wr * 16 + (lane & 15);

#pragma unroll 1
    for (int level = 0; level < 2; ++level) {
        const float* We  = level ? W2  : W1;
        const float* be  = level ? b2  : b1;
        const float* Wd  = level ? Wd2 : Wd1;
        const float* bdv = level ? bd2 : bd1;
        const int KSEL   = level ? K2 : K1;
        const int NPASS  = (level ? HID2 : HID1) / FTILE;

        if (tid < ROWS) { s_cnt[tid] = 0; s_scale[tid] = 1.0f; s_act[tid] = 1; }
        __syncthreads();

        // ============== approx GEMM + threshold push (with retry) ==============
#pragma unroll 1
        for (int attempt = 0; attempt < 8; ++attempt) {
            if (tid < ROWS) s_thr[tid] = s_act[tid] ? s_sig[tid] * s_scale[tid] : 3.4e38f;
            __syncthreads();
            const int rb = wr * 16 + g * 4;
            float t0 = s_thr[rb + 0], t1 = s_thr[rb + 1];
            float t2 = s_thr[rb + 2], t3 = s_thr[rb + 3];

#pragma unroll 1
            for (int p = 0; p < NPASS; ++p) {
                {   // stage B tile: 256 features x 64 k, bf16-hi, swizzled
                    const int f  = tid >> 2;
                    const int c0 = (tid & 3) * 4;
                    const float4* wrow = (const float4*)(We + (size_t)(p * FTILE + f) * D64);
#pragma unroll
                    for (int i = 0; i < 4; ++i) {
                        int c = c0 + i;
                        float4 wv = wrow[c];
                        unsigned long long pk = (unsigned long long)f2bf(wv.x)
                                             | ((unsigned long long)f2bf(wv.y) << 16)
                                             | ((unsigned long long)f2bf(wv.z) << 32)
                                             | ((unsigned long long)f2bf(wv.w) << 48);
                        *(unsigned long long*)&s_b[f * D64 + 8 * ((c >> 1) ^ (f & 7)) + (c & 1) * 4] = pk;
                    }
                }
                __syncthreads();
                {   // MFMA: wave computes 16 rows x 64 feats; push approx > thr
                    bf16x8 a0 = *(const bf16x8*)&s_ah[arow * D64 + 8 * ((0 + g) ^ (arow & 7))];
                    bf16x8 a1 = *(const bf16x8*)&s_ah[arow * D64 + 8 * ((4 + g) ^ (arow & 7))];
#pragma unroll
                    for (int sub = 0; sub < 4; ++sub) {
                        const int fl = wc * 64 + sub * 16 + (lane & 15);
                        bf16x8 b0  = *(const bf16x8*)&s_b[fl * D64 + 8 * ((0 + g) ^ (fl & 7))];
                        bf16x8 b1v = *(const bf16x8*)&s_b[fl * D64 + 8 * ((4 + g) ^ (fl & 7))];
                        f32x4 acc = {0.f, 0.f, 0.f, 0.f};
                        acc = __builtin_amdgcn_mfma_f32_16x16x32_bf16(a0, b0,  acc, 0, 0, 0);
                        acc = __builtin_amdgcn_mfma_f32_16x16x32_bf16(a1, b1v, acc, 0, 0, 0);
                        const int colg = p * FTILE + fl;
                        const float bias = be[colg];
                        float v0 = fmaxf(acc[0] + bias, 0.f);
                        float v1 = fmaxf(acc[1] + bias, 0.f);
                        float v2 = fmaxf(acc[2] + bias, 0.f);
                        float v3 = fmaxf(acc[3] + bias, 0.f);
                        const int rb2 = wr * 16 + g * 4;
                        if (v0 > t0) { int s = atomicAdd(&s_cnt[rb2 + 0], 1); if (s < CAP) s_buf[(rb2 + 0) * CAP + s] = make_uint2(__float_as_uint(v0), (unsigned)colg); }
                        if (v1 > t1) { int s = atomicAdd(&s_cnt[rb2 + 1], 1); if (s < CAP) s_buf[(rb2 + 1) * CAP + s] = make_uint2(__float_as_uint(v1), (unsigned)colg); }
                        if (v2 > t2) { int s = atomicAdd(&s_cnt[rb2 + 2], 1); if (s < CAP) s_buf[(rb2 + 2) * CAP + s] = make_uint2(__float_as_uint(v2), (unsigned)colg); }
                        if (v3 > t3) { int s = atomicAdd(&s_cnt[rb2 + 3], 1); if (s < CAP) s_buf[(rb2 + 3) * CAP + s] = make_uint2(__float_as_uint(v3), (unsigned)colg); }
                    }
                }
                __syncthreads();
            }
            if (tid == 0) s_anybad = 0;
            __syncthreads();
            if (tid < ROWS) {
                int c = s_cnt[tid];
                bool lo = (c < KSEL), hi = (c > CAP);
                bool bad = (lo || hi) && (attempt < 7);
                s_act[tid] = bad ? 1 : 0;
                if (bad) { s_scale[tid] *= (lo ? 0.85f : 1.15f); s_cnt[tid] = 0; atomicAdd(&s_anybad, 1); }
            }
            __syncthreads();
            if (s_anybad == 0) break;
        }

        // ===== exact recompute (4 cand/wave) + exact select + decode =====
#pragma unroll 1
        for (int q2 = 0; q2 < 4; ++q2) {
            const int r = wu * 4 + q2;
            int n = s_cnt[r]; if (n > CAP) n = CAP;
            const int kq = lane & 15;
            const int cg = lane >> 4;
            const float4 xv = ((const float4*)s_xf32)[r * 16 + kq];
#pragma unroll 1
            for (int s = 0; s < n; s += 4) {
                const int sc = s + cg;
                unsigned j = (sc < n) ? s_buf[r * CAP + sc].y : 0u;
                float4 wv = ((const float4*)We)[(size_t)j * 16 + kq];
                float d = fmaf(wv.x, xv.x, fmaf(wv.y, xv.y, fmaf(wv.z, xv.z, wv.w * xv.w)));
                d += __shfl_xor(d, 1, 64); d += __shfl_xor(d, 2, 64);
                d += __shfl_xor(d, 4, 64); d += __shfl_xor(d, 8, 64);
                if (kq == 0 && sc < n)
                    s_buf[r * CAP + sc].x = __float_as_uint(fmaxf(d + be[j], 0.f));
            }
            // exact u64-key selection (value bits desc, ~idx for low-index ties)
            unsigned long long k0 = 0ull, k1 = 0ull, k2 = 0ull;
            if (lane < n)        { uint2 pp = s_buf[r * CAP + lane];       k0 = ((unsigned long long)pp.x << 32) | (unsigned)(~pp.y); }
            if (lane + 64 < n)   { uint2 pp = s_buf[r * CAP + lane + 64];  k1 = ((unsigned long long)pp.x << 32) | (unsigned)(~pp.y); }
            if (lane + 128 < n)  { uint2 pp = s_buf[r * CAP + lane + 128]; k2 = ((unsigned long long)pp.x << 32) | (unsigned)(~pp.y); }
            if (k1 > k0) { unsigned long long t = k0; k0 = k1; k1 = t; }
            if (k2 > k1) { unsigned long long t = k1; k1 = k2; k2 = t; }
            if (k1 > k0) { unsigned long long t = k0; k0 = k1; k1 = t; }
            unsigned savhi = 0u, savlo = 0u;
#pragma unroll 1
            for (int t = 0; t < KSEL; ++t) {
                unsigned long long m = wave_max_u64(k0);
                if (m == 0ull) break;
                if (lane == t) { savhi = (unsigned)(m >> 32); savlo = (unsigned)m; }
                if (k0 == m) { k0 = k1; k1 = k2; k2 = 0ull; }
            }
            // decode: rec = bdv + sum z_t * Wd[idx_t], 4-deep load batching
            float rec = bdv[lane];
#pragma unroll 1
            for (int t = 0; t < KSEL; t += 4) {
                unsigned h0 = __shfl(savhi, t + 0, 64), m0 = __shfl(savlo, t + 0, 64);
                unsigned h1 = __shfl(savhi, t + 1, 64), m1 = __shfl(savlo, t + 1, 64);
                unsigned h2 = __shfl(savhi, t + 2, 64), m2 = __shfl(savlo, t + 2, 64);
                unsigned h3 = __shfl(savhi, t + 3, 64), m3 = __shfl(savlo, t + 3, 64);
                unsigned i0 = h0 ? ~m0 : 0u, i1 = h1 ? ~m1 : 0u;
                unsigned i2 = h2 ? ~m2 : 0u, i3 = h3 ? ~m3 : 0u;
                float w0 = Wd[(size_t)i0 * D64 + lane];
                float w1 = Wd[(size_t)i1 * D64 + lane];
                float w2v = Wd[(size_t)i2 * D64 + lane];
                float w3 = Wd[(size_t)i3 * D64 + lane];
                rec = fmaf(__uint_as_float(h0), w0, rec);
                rec = fmaf(__uint_as_float(h1), w1, rec);
                rec = fmaf(__uint_as_float(h2), w2v, rec);
                rec = fmaf(__uint_as_float(h3), w3, rec);
            }
            if (level == 0) {
                float e = wave_sum_f32(rec * rec);
                if (lane == 0) s_sig[r] = 0.25f * sqrtf(e);   // 2*sigma for level 1
                s_xf32[r * D64 + lane] = rec;                 // recon0 (exact)
                s_ah[r * D64 + 8 * ((lane >> 3) ^ (r & 7)) + (lane & 7)] = f2bf(rec);
            } else {
                float rec0 = s_xf32[r * D64 + lane];
                out[(size_t)(rowbase + r) * D64 + lane] =
                    (1.0f / 1.5f) * rec0 + (0.5f / 1.5f) * rec;
            }
        }
        __syncthreads();   // recon0 buffers visible to all waves before level 1
    }
}

extern "C" void kernel_launch(void* const* d_in, const int* in_sizes, int n_in,
                              void* d_out, int out_size, void* d_ws, size_t ws_size,
                              hipStream_t stream) {
    (void)n_in; (void)out_size; (void)d_ws; (void)ws_size;
    const float* x   = (const float*)d_in[0];
    const float* W1  = (const float*)d_in[1];
    const float* b1  = (const float*)d_in[2];
    const float* Wd1 = (const float*)d_in[3];
    const float* bd1 = (const float*)d_in[4];
    const float* W2  = (const float*)d_in[5];
    const float* b2  = (const float*)d_in[6];
    const float* Wd2 = (const float*)d_in[7];
    const float* bd2 = (const float*)d_in[8];

    const int batch = in_sizes[0] / D64;     // 16384
    const int grid  = batch / ROWS;          // 256 blocks, 1 per CU

    sae_hier_mfma<<<grid, 1024, 0, stream>>>(x, W1, b1, Wd1, bd1, W2, b2, Wd2, bd2,
                                             (float*)d_out);
}